// Round 1
// baseline (221.439 us; speedup 1.0000x reference)
//
#include <hip/hip_runtime.h>
#include <math.h>

#define SQRT3F     1.7320508075688772f
#define SCALE_T    0.17677669529663687f    // 1/sqrt(32)
#define SCALE_M1   0.025515518153991442f   // C_SCALAR/sqrt(32)
#define SCALE_M2   0.014731391274719739f   // C_SCALAR*inv_sqrt3/sqrt(32)
#define SCALE_M34  0.036084391824351615f   // C_SCALAR/4  (== C_VECTOR*inv_sqrt3/sqrt(16))

// ---------------------------------------------------------------------------
// Precompute: T = emb @ W_s2n * 1/sqrt(32)  (100x32)
//             Ms[l] (48x32) = [W1@Ws * sM1 ; W4@Ws * sM2]
//             Mv[l] (48x16) = [W2@Wv * sM34 ; W3@Wv * sM34]
// ---------------------------------------------------------------------------
__global__ void precompute_kernel(const float* __restrict__ emb,
                                  const float* __restrict__ W_s2n,
                                  const float* __restrict__ W1,
                                  const float* __restrict__ W2,
                                  const float* __restrict__ W3,
                                  const float* __restrict__ W4,
                                  const float* __restrict__ Ws,
                                  const float* __restrict__ Wv,
                                  float* __restrict__ T,
                                  float* __restrict__ Ms,
                                  float* __restrict__ Mv)
{
    const int total = 100*32 + 3*48*32 + 3*48*16;  // 3200 + 4608 + 2304
    for (int idx = blockIdx.x * blockDim.x + threadIdx.x; idx < total;
         idx += gridDim.x * blockDim.x) {
        if (idx < 3200) {
            int r = idx >> 5, c = idx & 31;
            float acc = 0.f;
            for (int k = 0; k < 32; ++k) acc += emb[r*32 + k] * W_s2n[k*32 + c];
            T[idx] = acc * SCALE_T;
        } else if (idx < 3200 + 3*1536) {
            int tix = idx - 3200;
            int l = tix / 1536, rem = tix % 1536;
            int u = rem >> 5, w = rem & 31;
            float acc = 0.f;
            if (u < 32) {
                for (int k = 0; k < 32; ++k)
                    acc += W1[l*1024 + u*32 + k] * Ws[l*1024 + k*32 + w];
                acc *= SCALE_M1;
            } else {
                int uu = u - 32;
                for (int k = 0; k < 32; ++k)
                    acc += W4[l*512 + uu*32 + k] * Ws[l*1024 + k*32 + w];
                acc *= SCALE_M2;
            }
            Ms[l*1536 + u*32 + w] = acc;
        } else {
            int tix = idx - 3200 - 3*1536;
            int l = tix / 768, rem = tix % 768;
            int u = rem >> 4, w = rem & 15;
            float acc = 0.f;
            if (u < 32) {
                for (int k = 0; k < 16; ++k)
                    acc += W2[l*512 + u*16 + k] * Wv[l*256 + k*16 + w];
            } else {
                int uu = u - 32;
                for (int k = 0; k < 16; ++k)
                    acc += W3[l*256 + uu*16 + k] * Wv[l*256 + k*16 + w];
            }
            Mv[l*768 + u*16 + w] = acc * SCALE_M34;
        }
    }
}

// ---------------------------------------------------------------------------
// rowptr[n] = lower_bound(src, n): edges sorted by src (np.nonzero C-order).
// ---------------------------------------------------------------------------
__global__ void rowptr_kernel(const int* __restrict__ src, int E, int N,
                              int* __restrict__ rowptr)
{
    int n = blockIdx.x * blockDim.x + threadIdx.x;
    if (n > N) return;
    int lo = 0, hi = E;
    while (lo < hi) {
        int mid = (lo + hi) >> 1;
        if (src[mid] < n) lo = mid + 1; else hi = mid;
    }
    rowptr[n] = lo;
}

// ---------------------------------------------------------------------------
// s0[n,c] = T[z[n], c];  v0 = 0
// ---------------------------------------------------------------------------
__global__ void init_kernel(const int* __restrict__ z, const float* __restrict__ T,
                            float* __restrict__ s0, float* __restrict__ v0, int N)
{
    int idx = blockIdx.x * blockDim.x + threadIdx.x;
    if (idx < N*32) {
        int n = idx >> 5, c = idx & 31;
        s0[idx] = T[z[n]*32 + c];
    }
    if (idx < N*48) v0[idx] = 0.f;
}

// ---------------------------------------------------------------------------
// One message-passing layer.  4 lanes per node (quad). Lane t owns scalar
// channels 8t..8t+7 and vector channels 4t..4t+3. Gather over the node's
// out-edge block (== in-edges by symmetry, sh negated), then quad-shfl
// matmul with LDS-resident folded weights.
// ---------------------------------------------------------------------------
__launch_bounds__(256)
__global__ void layer_kernel(const float* __restrict__ s_in, const float* __restrict__ v_in,
                             float* __restrict__ s_out, float* __restrict__ v_out,
                             const float* __restrict__ pos,
                             const int* __restrict__ rowptr, const int* __restrict__ colv,
                             const float* __restrict__ Ms, const float* __restrict__ Mv,
                             int N)
{
    __shared__ float lMs[48*32];
    __shared__ float lMv[48*16];
    for (int i = threadIdx.x; i < 48*32; i += 256) lMs[i] = Ms[i];
    for (int i = threadIdx.x; i < 48*16; i += 256) lMv[i] = Mv[i];
    __syncthreads();

    const int n  = blockIdx.x * 64 + (threadIdx.x >> 2);
    const int t  = threadIdx.x & 3;
    const int qb = (threadIdx.x & 63) & ~3;   // quad base lane within wave
    if (n >= N) return;

    float a0[8]    = {0.f,0.f,0.f,0.f,0.f,0.f,0.f,0.f};
    float a1[8][3] = {};
    float a2[4][3] = {};
    float a3[4]    = {0.f,0.f,0.f,0.f};

    const float px = pos[3*n+0], py = pos[3*n+1], pz = pos[3*n+2];
    const int e0 = rowptr[n], e1 = rowptr[n+1];
    for (int e = e0; e < e1; ++e) {
        const int j = colv[e];
        float dx = px - pos[3*j+0];
        float dy = py - pos[3*j+1];
        float dz = pz - pos[3*j+2];
        float rinv = rsqrtf(dx*dx + dy*dy + dz*dz);
        float shx = SQRT3F * dx * rinv;
        float shy = SQRT3F * dy * rinv;
        float shz = SQRT3F * dz * rinv;

        const float4* sp = (const float4*)(s_in + (size_t)j*32 + 8*t);
        float4 sA = sp[0], sB = sp[1];
        const float4* vp = (const float4*)(v_in + (size_t)j*48 + 12*t);
        float4 vA = vp[0], vB = vp[1], vC = vp[2];

        float ss[8] = {sA.x,sA.y,sA.z,sA.w,sB.x,sB.y,sB.z,sB.w};
        #pragma unroll
        for (int k = 0; k < 8; ++k) {
            a0[k] += ss[k];
            a1[k][0] = fmaf(ss[k], shx, a1[k][0]);
            a1[k][1] = fmaf(ss[k], shy, a1[k][1]);
            a1[k][2] = fmaf(ss[k], shz, a1[k][2]);
        }
        float vv[4][3] = {{vA.x,vA.y,vA.z},{vA.w,vB.x,vB.y},
                          {vB.z,vB.w,vC.x},{vC.y,vC.z,vC.w}};
        #pragma unroll
        for (int k = 0; k < 4; ++k) {
            a2[k][0] += vv[k][0]; a2[k][1] += vv[k][1]; a2[k][2] += vv[k][2];
            a3[k] += vv[k][0]*shx + vv[k][1]*shy + vv[k][2]*shz;
        }
    }

    // ---- scalar outputs: my columns 8t..8t+7 ----
    float poA[4] = {0,0,0,0}, poB[4] = {0,0,0,0};
    #pragma unroll
    for (int tt = 0; tt < 4; ++tt) {
        #pragma unroll
        for (int k = 0; k < 8; ++k) {
            float a = __shfl(a0[k], qb + tt, 64);
            const float* row = lMs + (8*tt + k)*32 + 8*t;
            #pragma unroll
            for (int m = 0; m < 4; ++m) {
                poA[m] = fmaf(a, row[m],   poA[m]);
                poB[m] = fmaf(a, row[4+m], poB[m]);
            }
        }
        #pragma unroll
        for (int k = 0; k < 4; ++k) {
            float a = __shfl(a3[k], qb + tt, 64);
            const float* row = lMs + (32 + 4*tt + k)*32 + 8*t;
            #pragma unroll
            for (int m = 0; m < 4; ++m) {
                poA[m] = fmaf(a, row[m],   poA[m]);
                poB[m] = fmaf(a, row[4+m], poB[m]);
            }
        }
    }
    {
        const float* sip = s_in  + (size_t)n*32 + 8*t;
        float*       sop = s_out + (size_t)n*32 + 8*t;
        #pragma unroll
        for (int m = 0; m < 4; ++m) sop[m]   = sip[m]   + fmaxf(poA[m], 0.f);
        #pragma unroll
        for (int m = 0; m < 4; ++m) sop[4+m] = sip[4+m] + fmaxf(poB[m], 0.f);
    }

    // ---- vector outputs: my channels 4t..4t+3 (12 floats) ----
    float pv[12] = {};
    #pragma unroll
    for (int tt = 0; tt < 4; ++tt) {
        #pragma unroll
        for (int k = 0; k < 8; ++k) {
            float b0 = __shfl(a1[k][0], qb + tt, 64);
            float b1 = __shfl(a1[k][1], qb + tt, 64);
            float b2 = __shfl(a1[k][2], qb + tt, 64);
            const float* row = lMv + (8*tt + k)*16 + 4*t;
            #pragma unroll
            for (int m = 0; m < 4; ++m) {
                float r = row[m];
                pv[m*3+0] = fmaf(r, b0, pv[m*3+0]);
                pv[m*3+1] = fmaf(r, b1, pv[m*3+1]);
                pv[m*3+2] = fmaf(r, b2, pv[m*3+2]);
            }
        }
        #pragma unroll
        for (int k = 0; k < 4; ++k) {
            float b0 = __shfl(a2[k][0], qb + tt, 64);
            float b1 = __shfl(a2[k][1], qb + tt, 64);
            float b2 = __shfl(a2[k][2], qb + tt, 64);
            const float* row = lMv + (32 + 4*tt + k)*16 + 4*t;
            #pragma unroll
            for (int m = 0; m < 4; ++m) {
                float r = row[m];
                pv[m*3+0] = fmaf(r, b0, pv[m*3+0]);
                pv[m*3+1] = fmaf(r, b1, pv[m*3+1]);
                pv[m*3+2] = fmaf(r, b2, pv[m*3+2]);
            }
        }
    }
    {
        const float* vip = v_in  + (size_t)n*48 + 12*t;
        float*       vop = v_out + (size_t)n*48 + 12*t;
        #pragma unroll
        for (int m = 0; m < 12; ++m) vop[m] = vip[m] + fmaxf(pv[m], 0.f);
    }
}

// ---------------------------------------------------------------------------
// Pool: hg[g, f] = sum over the graph's 32 nodes of [s | v-flat]
// (batch = repeat(arange(B), 32) by construction -> graph g owns nodes 32g..)
// ---------------------------------------------------------------------------
__global__ void pool_kernel(const float* __restrict__ s, const float* __restrict__ v,
                            float* __restrict__ hg, int B)
{
    int idx = blockIdx.x * blockDim.x + threadIdx.x;
    if (idx >= B*80) return;
    int g = idx / 80, f = idx - g*80;
    int base = g * 32;
    float acc = 0.f;
    if (f < 32) {
        for (int k = 0; k < 32; ++k) acc += s[(size_t)(base+k)*32 + f];
    } else {
        int c = f - 32;
        for (int k = 0; k < 32; ++k) acc += v[(size_t)(base+k)*48 + c];
    }
    hg[idx] = acc;
}

// ---------------------------------------------------------------------------
// MLP head: out[g] = relu(hg[g] @ Wr1 + br1) @ Wr2 + br2.  One block/graph.
// ---------------------------------------------------------------------------
__launch_bounds__(256)
__global__ void mlp_kernel(const float* __restrict__ hg,
                           const float* __restrict__ Wr1, const float* __restrict__ br1,
                           const float* __restrict__ Wr2, const float* __restrict__ br2,
                           float* __restrict__ out, int B)
{
    __shared__ float x[80];
    __shared__ float h1[256];
    int g = blockIdx.x;
    if (threadIdx.x < 80) x[threadIdx.x] = hg[(size_t)g*80 + threadIdx.x];
    __syncthreads();
    int w = threadIdx.x;
    float acc = br1[w];
    for (int f = 0; f < 80; ++f) acc = fmaf(x[f], Wr1[f*256 + w], acc);
    h1[w] = fmaxf(acc, 0.f);
    __syncthreads();
    if (w < 128) {
        float acc2 = br2[w];
        for (int k = 0; k < 256; ++k) acc2 = fmaf(h1[k], Wr2[k*128 + w], acc2);
        out[(size_t)g*128 + w] = acc2;
    }
}

// ---------------------------------------------------------------------------
extern "C" void kernel_launch(void* const* d_in, const int* in_sizes, int n_in,
                              void* d_out, int out_size, void* d_ws, size_t ws_size,
                              hipStream_t stream)
{
    const float* pos   = (const float*)d_in[0];
    const int*   z     = (const int*)d_in[1];
    const int*   eidx  = (const int*)d_in[3];
    const float* emb   = (const float*)d_in[5];
    const float* W_s2n = (const float*)d_in[6];
    const float* W1    = (const float*)d_in[7];
    const float* W2    = (const float*)d_in[8];
    const float* W3    = (const float*)d_in[9];
    const float* W4    = (const float*)d_in[10];
    const float* Ws    = (const float*)d_in[11];
    const float* Wv    = (const float*)d_in[12];
    const float* Wr1   = (const float*)d_in[13];
    const float* br1   = (const float*)d_in[14];
    const float* Wr2   = (const float*)d_in[15];
    const float* br2   = (const float*)d_in[16];
    float* out = (float*)d_out;

    const int N = in_sizes[0] / 3;
    const int E = in_sizes[3] / 2;
    const int B = out_size / 128;

    const int* src = eidx;
    const int* col = eidx + E;

    // workspace layout (16B-aligned chunks)
    char* p = (char*)d_ws;
    float* T  = (float*)p;  p += 3200 * 4;
    float* Ms = (float*)p;  p += 3 * 1536 * 4;
    float* Mv = (float*)p;  p += 3 * 768 * 4;
    int* rowptr = (int*)p;  p += (((size_t)(N + 1) * 4 + 15) & ~(size_t)15);
    float* s0 = (float*)p;  p += (size_t)N * 32 * 4;
    float* s1 = (float*)p;  p += (size_t)N * 32 * 4;
    float* v0 = (float*)p;  p += (size_t)N * 48 * 4;
    float* v1 = (float*)p;  p += (size_t)N * 48 * 4;
    float* hg = (float*)p;  p += (size_t)B * 80 * 4;

    precompute_kernel<<<40, 256, 0, stream>>>(emb, W_s2n, W1, W2, W3, W4, Ws, Wv,
                                              T, Ms, Mv);
    rowptr_kernel<<<(N + 1 + 255) / 256, 256, 0, stream>>>(src, E, N, rowptr);
    init_kernel<<<((size_t)N * 48 + 255) / 256, 256, 0, stream>>>(z, T, s0, v0, N);

    float *si = s0, *vi = v0, *so = s1, *vo = v1;
    for (int l = 0; l < 3; ++l) {
        layer_kernel<<<(N + 63) / 64, 256, 0, stream>>>(si, vi, so, vo, pos,
                                                        rowptr, col,
                                                        Ms + l*1536, Mv + l*768, N);
        float* ts = si; si = so; so = ts;
        float* tv = vi; vi = vo; vo = tv;
    }

    pool_kernel<<<((size_t)B * 80 + 255) / 256, 256, 0, stream>>>(si, vi, hg, B);
    mlp_kernel<<<B, 256, 0, stream>>>(hg, Wr1, br1, Wr2, br2, out, B);
}